// Round 7
// baseline (109.469 us; speedup 1.0000x reference)
//
#include <hip/hip_runtime.h>

// upfirdn2d specialized: up=2, down=1, pad0=2, eff trailing pad 2,
// 4x4 kernel, input (1024, 128, 128) f32 -> output (1024, 256, 256) f32.
//
// Polyphase: output (2r+py, 2c+px) mixes input rows {r-1,r} (py=0) or
// {r,r+1} (py=1), same in x. w[ky][kx] = kernel[3-ky][3-kx] (conv flip).
//
// Row-pair per thread, NAMED SCALARS ONLY (R4/R6 lesson: local arrays +
// pointer lambdas -> scratch). 4 row loads up front, two emit passes,
// 8x float4 nontemporal stores (4 output rows x 8 cols).

typedef float f4 __attribute__((ext_vector_type(4)));

#define LDROW(rr, A)                                                      \
  if ((rr) >= 0 && (rr) < H) {                                            \
    const float* row = xi + (rr) * W + x0;                                \
    const f4 v = *reinterpret_cast<const f4*>(row);                       \
    A##0 = (c4 > 0) ? row[-1] : 0.f;                                      \
    A##1 = v.x; A##2 = v.y; A##3 = v.z; A##4 = v.w;                       \
    A##5 = (c4 < 31) ? row[4] : 0.f;                                      \
  } else {                                                                \
    A##0 = A##1 = A##2 = A##3 = A##4 = A##5 = 0.f;                        \
  }

#define EMIT(A, B, C, orow0)                                              \
  {                                                                       \
    f4 u0, u1, l0, l1;                                                    \
    u0.x = w00*A##0 + w02*A##1 + w20*B##0 + w22*B##1;                     \
    u0.y = w01*A##1 + w03*A##2 + w21*B##1 + w23*B##2;                     \
    u0.z = w00*A##1 + w02*A##2 + w20*B##1 + w22*B##2;                     \
    u0.w = w01*A##2 + w03*A##3 + w21*B##2 + w23*B##3;                     \
    u1.x = w00*A##2 + w02*A##3 + w20*B##2 + w22*B##3;                     \
    u1.y = w01*A##3 + w03*A##4 + w21*B##3 + w23*B##4;                     \
    u1.z = w00*A##3 + w02*A##4 + w20*B##3 + w22*B##4;                     \
    u1.w = w01*A##4 + w03*A##5 + w21*B##4 + w23*B##5;                     \
    l0.x = w10*B##0 + w12*B##1 + w30*C##0 + w32*C##1;                     \
    l0.y = w11*B##1 + w13*B##2 + w31*C##1 + w33*C##2;                     \
    l0.z = w10*B##1 + w12*B##2 + w30*C##1 + w32*C##2;                     \
    l0.w = w11*B##2 + w13*B##3 + w31*C##2 + w33*C##3;                     \
    l1.x = w10*B##2 + w12*B##3 + w30*C##2 + w32*C##3;                     \
    l1.y = w11*B##3 + w13*B##4 + w31*C##3 + w33*C##4;                     \
    l1.z = w10*B##3 + w12*B##4 + w30*C##3 + w32*C##4;                     \
    l1.w = w11*B##4 + w13*B##5 + w31*C##4 + w33*C##5;                     \
    __builtin_nontemporal_store(u0, reinterpret_cast<f4*>(orow0));        \
    __builtin_nontemporal_store(u1, reinterpret_cast<f4*>((orow0) + 4));  \
    __builtin_nontemporal_store(l0, reinterpret_cast<f4*>((orow0) + OW)); \
    __builtin_nontemporal_store(l1, reinterpret_cast<f4*>((orow0) + OW + 4)); \
  }

__global__ __launch_bounds__(256) void upfirdn2d_up2_kernel(
    const float* __restrict__ x, const float* __restrict__ kern,
    float* __restrict__ out) {
  constexpr int H = 128, W = 128, OW = 256;

  const int tid = threadIdx.x;
  const int c4  = tid & 31;                             // float4 col 0..31
  const int pr  = ((blockIdx.x & 7) << 3) | (tid >> 5); // row-pair 0..63
  const int img = blockIdx.x >> 3;                      // 0..1023
  const int r0  = pr << 1;                              // first input row

  // Flipped 4x4 kernel weights (uniform -> scalar regs).
  const float w00 = kern[15], w01 = kern[14], w02 = kern[13], w03 = kern[12];
  const float w10 = kern[11], w11 = kern[10], w12 = kern[9],  w13 = kern[8];
  const float w20 = kern[7],  w21 = kern[6],  w22 = kern[5],  w23 = kern[4];
  const float w30 = kern[3],  w31 = kern[2],  w32 = kern[1],  w33 = kern[0];

  const float* xi = x + (size_t)img * H * W;
  const int x0 = c4 << 2;  // first input col of this thread

  float t0, t1, t2, t3, t4, t5;
  float m0, m1, m2, m3, m4, m5;
  float b0, b1, b2, b3, b4, b5;
  float c0, c1, c2, c3, c4_, c5;
  // (c4_ avoids clash with lane index c4)
  LDROW(r0 - 1, t);
  LDROW(r0,     m);
  LDROW(r0 + 1, b);
  // expand LDROW for 'c' manually due to c4 name clash
  if (r0 + 2 < H) {
    const float* row = xi + (r0 + 2) * W + x0;
    const f4 v = *reinterpret_cast<const f4*>(row);
    c0 = (c4 > 0) ? row[-1] : 0.f;
    c1 = v.x; c2 = v.y; c3 = v.z; c4_ = v.w;
    c5 = (c4 < 31) ? row[4] : 0.f;
  } else {
    c0 = c1 = c2 = c3 = c4_ = c5 = 0.f;
  }

  float* obase = out + (size_t)img * OW * OW + (size_t)(2 * r0) * OW + 2 * x0;
  EMIT(t, m, b, obase);  // output rows 2r0, 2r0+1

  // Second pass: A=m, B=b, C=c (c4_ stands in for c##4)
  {
    f4 u0, u1, l0, l1;
    u0.x = w00*m0 + w02*m1 + w20*b0 + w22*b1;
    u0.y = w01*m1 + w03*m2 + w21*b1 + w23*b2;
    u0.z = w00*m1 + w02*m2 + w20*b1 + w22*b2;
    u0.w = w01*m2 + w03*m3 + w21*b2 + w23*b3;
    u1.x = w00*m2 + w02*m3 + w20*b2 + w22*b3;
    u1.y = w01*m3 + w03*m4 + w21*b3 + w23*b4;
    u1.z = w00*m3 + w02*m4 + w20*b3 + w22*b4;
    u1.w = w01*m4 + w03*m5 + w21*b4 + w23*b5;
    l0.x = w10*b0 + w12*b1 + w30*c0 + w32*c1;
    l0.y = w11*b1 + w13*b2 + w31*c1 + w33*c2;
    l0.z = w10*b1 + w12*b2 + w30*c1 + w32*c2;
    l0.w = w11*b2 + w13*b3 + w31*c2 + w33*c3;
    l1.x = w10*b2 + w12*b3 + w30*c2 + w32*c3;
    l1.y = w11*b3 + w13*b4 + w31*c3 + w33*c4_;
    l1.z = w10*b3 + w12*b4 + w30*c3 + w32*c4_;
    l1.w = w11*b4 + w13*b5 + w31*c4_ + w33*c5;
    float* orow0 = obase + 2 * OW;
    __builtin_nontemporal_store(u0, reinterpret_cast<f4*>(orow0));
    __builtin_nontemporal_store(u1, reinterpret_cast<f4*>(orow0 + 4));
    __builtin_nontemporal_store(l0, reinterpret_cast<f4*>(orow0 + OW));
    __builtin_nontemporal_store(l1, reinterpret_cast<f4*>(orow0 + OW + 4));
  }
}

extern "C" void kernel_launch(void* const* d_in, const int* in_sizes, int n_in,
                              void* d_out, int out_size, void* d_ws, size_t ws_size,
                              hipStream_t stream) {
  const float* x    = (const float*)d_in[0];
  const float* kern = (const float*)d_in[1];
  float* out        = (float*)d_out;
  // 1024 images x 8 blocks (8 row-pairs x 32 float4-cols per block).
  upfirdn2d_up2_kernel<<<dim3(1024 * 8), dim3(256), 0, stream>>>(x, kern, out);
}